// Round 1
// baseline (2540.613 us; speedup 1.0000x reference)
//
#include <hip/hip_runtime.h>

// Problem constants
constexpr int B = 8, N = 10000, C_IN = 16, T = 24, C_OUT = 32, E = 160000;
constexpr int S = B * T;       // 192 graph slices
constexpr int H1 = 64;         // 4*C_IN
constexpr int H2 = 128;        // 4*C_OUT

// ---------------- CSR build ----------------
__global__ void hist_kernel(const int* __restrict__ dst, int* __restrict__ counts) {
    int e = blockIdx.x * blockDim.x + threadIdx.x;
    if (e < E) atomicAdd(&counts[dst[e]], 1);
}

// single-block exclusive scan over N counts -> offs[0..N]
__global__ void scan_kernel(const int* __restrict__ counts, int* __restrict__ offs) {
    __shared__ int lds[1024];
    __shared__ int base_s;
    int tid = threadIdx.x;
    if (tid == 0) base_s = 0;
    __syncthreads();
    constexpr int CHUNKS = (N + 1023) / 1024;
    for (int chunk = 0; chunk < CHUNKS; ++chunk) {
        int i = chunk * 1024 + tid;
        int v = (i < N) ? counts[i] : 0;
        lds[tid] = v;
        __syncthreads();
        for (int off = 1; off < 1024; off <<= 1) {
            int add = (tid >= off) ? lds[tid - off] : 0;
            __syncthreads();
            lds[tid] += add;
            __syncthreads();
        }
        int incl = lds[tid];
        int excl = base_s + incl - v;
        if (i < N) offs[i] = excl;
        if (i == N - 1) offs[N] = excl + v;
        __syncthreads();
        if (tid == 1023) base_s += lds[1023];
        __syncthreads();
    }
}

__global__ void fill_kernel(const int* __restrict__ src, const int* __restrict__ dst,
                            const int* __restrict__ offs, int* __restrict__ cursor,
                            int* __restrict__ csr) {
    int e = blockIdx.x * blockDim.x + threadIdx.x;
    if (e >= E) return;
    int d = dst[e];
    int pos = atomicAdd(&cursor[d], 1);
    csr[offs[d] + pos] = src[e];
}

// ---------------- layout transform: (B,N,C,T) -> (S=B*T, N, C) ----------------
__global__ void transpose_kernel(const float* __restrict__ x, float* __restrict__ x0) {
    int bn = blockIdx.x;                 // b*N + n
    int tid = threadIdx.x;               // c*T + t, 384 threads
    int c = tid / T, t = tid - c * T;
    float v = x[(size_t)bn * (C_IN * T) + tid];
    int b = bn / N, n = bn - b * N;
    x0[((size_t)(b * T + t) * N + n) * C_IN + c] = v;
}

// ---------------- layer 1: gather + MLP (16 -> 64 -> 32) ----------------
__global__ __launch_bounds__(256) void mlp1_kernel(
    const float* __restrict__ x0, const int* __restrict__ offs, const int* __restrict__ csr,
    const float* __restrict__ W1, const float* __restrict__ b1,
    const float* __restrict__ W2, const float* __restrict__ b2,
    float* __restrict__ h1out) {
    __shared__ float W1t[C_IN * H1];    // W1t[j*16+c] = W1[c*64+j]
    __shared__ float W2s[H1 * C_OUT];   // row-major [j][o]
    __shared__ float b1s[H1];
    __shared__ float b2s[C_OUT];
    for (int i = threadIdx.x; i < C_IN * H1; i += 256) {
        int j = i >> 4, c = i & 15;
        W1t[i] = W1[c * H1 + j];
    }
    for (int i = threadIdx.x; i < H1 * C_OUT; i += 256) W2s[i] = W2[i];
    if (threadIdx.x < H1) b1s[threadIdx.x] = b1[threadIdx.x];
    if (threadIdx.x < C_OUT) b2s[threadIdx.x] = b2[threadIdx.x];
    __syncthreads();

    int p = blockIdx.x * 256 + threadIdx.x;
    if (p >= S * N / 2) return;
    int row0 = p * 2;
    int s = row0 / N;
    int n0 = row0 - s * N;               // even; n0+1 in same slice (N even)
    const float* xs = x0 + (size_t)s * N * C_IN;

    float ha[C_IN], hb[C_IN];
    {
        const float4* r = reinterpret_cast<const float4*>(xs + (size_t)n0 * C_IN);
        #pragma unroll
        for (int q = 0; q < 4; ++q) { float4 v = r[q];     ha[4*q]=v.x; ha[4*q+1]=v.y; ha[4*q+2]=v.z; ha[4*q+3]=v.w; }
        #pragma unroll
        for (int q = 0; q < 4; ++q) { float4 v = r[q + 4]; hb[4*q]=v.x; hb[4*q+1]=v.y; hb[4*q+2]=v.z; hb[4*q+3]=v.w; }
    }
    // gather in-neighbors
    int beg = offs[n0], end = offs[n0 + 1];
    for (int e = beg; e < end; ++e) {
        int sv = csr[e];
        const float4* rr = reinterpret_cast<const float4*>(xs + (size_t)sv * C_IN);
        #pragma unroll
        for (int q = 0; q < 4; ++q) { float4 v = rr[q]; ha[4*q]+=v.x; ha[4*q+1]+=v.y; ha[4*q+2]+=v.z; ha[4*q+3]+=v.w; }
    }
    beg = offs[n0 + 1]; end = offs[n0 + 2];
    for (int e = beg; e < end; ++e) {
        int sv = csr[e];
        const float4* rr = reinterpret_cast<const float4*>(xs + (size_t)sv * C_IN);
        #pragma unroll
        for (int q = 0; q < 4; ++q) { float4 v = rr[q]; hb[4*q]+=v.x; hb[4*q+1]+=v.y; hb[4*q+2]+=v.z; hb[4*q+3]+=v.w; }
    }

    float acca[C_OUT], accb[C_OUT];
    #pragma unroll
    for (int o = 0; o < C_OUT; ++o) { acca[o] = b2s[o]; accb[o] = b2s[o]; }
    for (int j = 0; j < H1; ++j) {
        float tj0 = b1s[j], tj1 = b1s[j];
        const float4* w1r = reinterpret_cast<const float4*>(&W1t[j * C_IN]);
        #pragma unroll
        for (int q = 0; q < 4; ++q) {
            float4 w = w1r[q];
            tj0 += ha[4*q]*w.x + ha[4*q+1]*w.y + ha[4*q+2]*w.z + ha[4*q+3]*w.w;
            tj1 += hb[4*q]*w.x + hb[4*q+1]*w.y + hb[4*q+2]*w.z + hb[4*q+3]*w.w;
        }
        tj0 = fmaxf(tj0, 0.f); tj1 = fmaxf(tj1, 0.f);
        const float4* w2r = reinterpret_cast<const float4*>(&W2s[j * C_OUT]);
        #pragma unroll
        for (int q = 0; q < 8; ++q) {
            float4 w = w2r[q];
            acca[4*q]+=tj0*w.x; acca[4*q+1]+=tj0*w.y; acca[4*q+2]+=tj0*w.z; acca[4*q+3]+=tj0*w.w;
            accb[4*q]+=tj1*w.x; accb[4*q+1]+=tj1*w.y; accb[4*q+2]+=tj1*w.z; accb[4*q+3]+=tj1*w.w;
        }
    }
    float4* d0 = reinterpret_cast<float4*>(h1out + (size_t)row0 * C_OUT);
    #pragma unroll
    for (int q = 0; q < 8; ++q) d0[q]     = make_float4(acca[4*q], acca[4*q+1], acca[4*q+2], acca[4*q+3]);
    #pragma unroll
    for (int q = 0; q < 8; ++q) d0[8 + q] = make_float4(accb[4*q], accb[4*q+1], accb[4*q+2], accb[4*q+3]);
}

// ---------------- layer 2: gather + MLP (32 -> 128 -> 32) + relu + output scatter ----------------
__global__ __launch_bounds__(256) void mlp2_kernel(
    const float* __restrict__ h1, const int* __restrict__ offs, const int* __restrict__ csr,
    const float* __restrict__ W3, const float* __restrict__ b3,
    const float* __restrict__ W4, const float* __restrict__ b4,
    float* __restrict__ out) {
    __shared__ float W3t[C_OUT * H2];   // W3t[j*32+c] = W3[c*128+j]
    __shared__ float W4s[H2 * C_OUT];   // row-major [j][o]
    __shared__ float b3s[H2];
    __shared__ float b4s[C_OUT];
    for (int i = threadIdx.x; i < C_OUT * H2; i += 256) {
        int j = i >> 5, c = i & 31;
        W3t[i] = W3[c * H2 + j];
    }
    for (int i = threadIdx.x; i < H2 * C_OUT; i += 256) W4s[i] = W4[i];
    if (threadIdx.x < H2) b3s[threadIdx.x] = b3[threadIdx.x];
    if (threadIdx.x < C_OUT) b4s[threadIdx.x] = b4[threadIdx.x];
    __syncthreads();

    int p = blockIdx.x * 256 + threadIdx.x;
    if (p >= S * N / 2) return;
    int row0 = p * 2;
    int s = row0 / N;
    int n0 = row0 - s * N;
    const float* hs = h1 + (size_t)s * N * C_OUT;

    float ha[C_OUT], hb[C_OUT];
    {
        const float4* r = reinterpret_cast<const float4*>(hs + (size_t)n0 * C_OUT);
        #pragma unroll
        for (int q = 0; q < 8; ++q) { float4 v = r[q];     ha[4*q]=v.x; ha[4*q+1]=v.y; ha[4*q+2]=v.z; ha[4*q+3]=v.w; }
        #pragma unroll
        for (int q = 0; q < 8; ++q) { float4 v = r[q + 8]; hb[4*q]=v.x; hb[4*q+1]=v.y; hb[4*q+2]=v.z; hb[4*q+3]=v.w; }
    }
    int beg = offs[n0], end = offs[n0 + 1];
    for (int e = beg; e < end; ++e) {
        int sv = csr[e];
        const float4* rr = reinterpret_cast<const float4*>(hs + (size_t)sv * C_OUT);
        #pragma unroll
        for (int q = 0; q < 8; ++q) { float4 v = rr[q]; ha[4*q]+=v.x; ha[4*q+1]+=v.y; ha[4*q+2]+=v.z; ha[4*q+3]+=v.w; }
    }
    beg = offs[n0 + 1]; end = offs[n0 + 2];
    for (int e = beg; e < end; ++e) {
        int sv = csr[e];
        const float4* rr = reinterpret_cast<const float4*>(hs + (size_t)sv * C_OUT);
        #pragma unroll
        for (int q = 0; q < 8; ++q) { float4 v = rr[q]; hb[4*q]+=v.x; hb[4*q+1]+=v.y; hb[4*q+2]+=v.z; hb[4*q+3]+=v.w; }
    }

    float acca[C_OUT], accb[C_OUT];
    #pragma unroll
    for (int o = 0; o < C_OUT; ++o) { acca[o] = b4s[o]; accb[o] = b4s[o]; }
    for (int j = 0; j < H2; ++j) {
        float tj0 = b3s[j], tj1 = b3s[j];
        const float4* w3r = reinterpret_cast<const float4*>(&W3t[j * C_OUT]);
        #pragma unroll
        for (int q = 0; q < 8; ++q) {
            float4 w = w3r[q];
            tj0 += ha[4*q]*w.x + ha[4*q+1]*w.y + ha[4*q+2]*w.z + ha[4*q+3]*w.w;
            tj1 += hb[4*q]*w.x + hb[4*q+1]*w.y + hb[4*q+2]*w.z + hb[4*q+3]*w.w;
        }
        tj0 = fmaxf(tj0, 0.f); tj1 = fmaxf(tj1, 0.f);
        const float4* w4r = reinterpret_cast<const float4*>(&W4s[j * C_OUT]);
        #pragma unroll
        for (int q = 0; q < 8; ++q) {
            float4 w = w4r[q];
            acca[4*q]+=tj0*w.x; acca[4*q+1]+=tj0*w.y; acca[4*q+2]+=tj0*w.z; acca[4*q+3]+=tj0*w.w;
            accb[4*q]+=tj1*w.x; accb[4*q+1]+=tj1*w.y; accb[4*q+2]+=tj1*w.z; accb[4*q+3]+=tj1*w.w;
        }
    }
    // output: (B, N, C_OUT, T), s = b*T + t
    int bb = s / T, t = s - bb * T;
    size_t obase = ((size_t)(bb * N + n0) * C_OUT) * T + t;
    #pragma unroll
    for (int c = 0; c < C_OUT; ++c) out[obase + (size_t)c * T] = fmaxf(acca[c], 0.f);
    obase += (size_t)C_OUT * T;
    #pragma unroll
    for (int c = 0; c < C_OUT; ++c) out[obase + (size_t)c * T] = fmaxf(accb[c], 0.f);
}

extern "C" void kernel_launch(void* const* d_in, const int* in_sizes, int n_in,
                              void* d_out, int out_size, void* d_ws, size_t ws_size,
                              hipStream_t stream) {
    const float* x   = (const float*)d_in[0];
    const int*   ei  = (const int*)d_in[1];      // (2,E) int32
    const float* W1  = (const float*)d_in[2];
    const float* b1  = (const float*)d_in[3];
    const float* W2  = (const float*)d_in[4];
    const float* b2  = (const float*)d_in[5];
    const float* W3  = (const float*)d_in[6];
    const float* b3  = (const float*)d_in[7];
    const float* W4  = (const float*)d_in[8];
    const float* b4  = (const float*)d_in[9];
    float* out = (float*)d_out;

    const int* srcp = ei;
    const int* dstp = ei + E;

    // workspace layout
    char* ws = (char*)d_ws;
    float* x0 = (float*)ws;                                   // S*N*C_IN  = 30.72M floats
    float* h1 = (float*)(ws + (size_t)S * N * C_IN * 4);      // S*N*C_OUT = 61.44M floats
    char* meta = ws + (size_t)S * N * C_IN * 4 + (size_t)S * N * C_OUT * 4;
    int* counts = (int*)meta;            // N
    int* offs   = counts + N;            // N+1
    int* cursor = offs + N + 1;          // N
    int* csr    = cursor + N;            // E

    hipMemsetAsync(counts, 0, (size_t)(N + (N + 1) + N) * sizeof(int), stream);

    hist_kernel<<<(E + 255) / 256, 256, 0, stream>>>(dstp, counts);
    scan_kernel<<<1, 1024, 0, stream>>>(counts, offs);
    fill_kernel<<<(E + 255) / 256, 256, 0, stream>>>(srcp, dstp, offs, cursor, csr);

    transpose_kernel<<<B * N, C_IN * T, 0, stream>>>(x, x0);

    int rows2 = S * N / 2;               // 960000 thread-pairs
    int grid = (rows2 + 255) / 256;      // 3750
    mlp1_kernel<<<grid, 256, 0, stream>>>(x0, offs, csr, W1, b1, W2, b2, h1);
    mlp2_kernel<<<grid, 256, 0, stream>>>(h1, offs, csr, W3, b3, W4, b4, out);
}

// Round 4
// 1891.289 us; speedup vs baseline: 1.3433x; 1.3433x over previous
//
#include <hip/hip_runtime.h>

// Problem constants
constexpr int B = 8, N = 10000, C_IN = 16, T = 24, C_OUT = 32, E = 160000;
constexpr int S = B * T;                 // 192 graph slices
constexpr int H1 = 64;                   // 4*C_IN
constexpr int H2 = 128;                  // 4*C_OUT
constexpr int NXCD = 8;
constexpr int SPX = S / NXCD;            // 24 slices per XCD
constexpr int BPS = (N + 511) / 512;     // 20 blocks per slice (256 thr x 2 rows)
constexpr int GRID_MLP = NXCD * SPX * BPS;  // 3840

// ---------------- CSR build ----------------
__global__ void hist_kernel(const int* __restrict__ dst, int* __restrict__ counts) {
    int e = blockIdx.x * blockDim.x + threadIdx.x;
    if (e < E) atomicAdd(&counts[dst[e]], 1);
}

__global__ void scan_kernel(const int* __restrict__ counts, int* __restrict__ offs) {
    __shared__ int lds[1024];
    __shared__ int base_s;
    int tid = threadIdx.x;
    if (tid == 0) base_s = 0;
    __syncthreads();
    constexpr int CHUNKS = (N + 1023) / 1024;
    for (int chunk = 0; chunk < CHUNKS; ++chunk) {
        int i = chunk * 1024 + tid;
        int v = (i < N) ? counts[i] : 0;
        lds[tid] = v;
        __syncthreads();
        for (int off = 1; off < 1024; off <<= 1) {
            int add = (tid >= off) ? lds[tid - off] : 0;
            __syncthreads();
            lds[tid] += add;
            __syncthreads();
        }
        int incl = lds[tid];
        int excl = base_s + incl - v;
        if (i < N) offs[i] = excl;
        if (i == N - 1) offs[N] = excl + v;
        __syncthreads();
        if (tid == 1023) base_s += lds[1023];
        __syncthreads();
    }
}

__global__ void fill_kernel(const int* __restrict__ src, const int* __restrict__ dst,
                            const int* __restrict__ offs, int* __restrict__ cursor,
                            int* __restrict__ csr) {
    int e = blockIdx.x * blockDim.x + threadIdx.x;
    if (e >= E) return;
    int d = dst[e];
    int pos = atomicAdd(&cursor[d], 1);
    csr[offs[d] + pos] = src[e];
}

// ---------------- input transpose: (B,N,C,T) -> (S=B*T, N, C), LDS-tiled ----------------
// block: (b, tile of 16 n).  6144 elements per tile.
__global__ __launch_bounds__(256) void in_transpose_kernel(const float* __restrict__ x,
                                                           float* __restrict__ x0) {
    __shared__ float lds[16 * 400];          // [n_l][c*25 + t], padded
    int b = blockIdx.x / (N / 16);
    int tile = blockIdx.x - b * (N / 16);
    int n0 = tile * 16;
    size_t ibase = ((size_t)b * N + n0) * (C_IN * T);
    // read phase: flat over 16*384
    #pragma unroll
    for (int it = 0; it < 24; ++it) {
        int f = it * 256 + threadIdx.x;      // f = n_l*384 + c*24 + t
        int n_l = f / 384;
        int rem = f - n_l * 384;
        int c = rem / 24;
        int t = rem - c * 24;
        lds[n_l * 400 + c * 25 + t] = x[ibase + f];
    }
    __syncthreads();
    // write phase: per t, 256 contiguous floats (16 n x 16 c)
    int n_l = threadIdx.x >> 4, c = threadIdx.x & 15;
    #pragma unroll
    for (int t = 0; t < T; ++t) {
        float v = lds[n_l * 400 + c * 25 + t];
        x0[((size_t)(b * T + t) * N + n0) * C_IN + threadIdx.x] = v;
    }
}

// ---------------- XCD-affinity mapping helper ----------------
__device__ inline void map_block(int i, int& slice, int& blk) {
    int xcd = i & (NXCD - 1);
    int j = i >> 3;
    slice = xcd * SPX + j / BPS;
    blk = j % BPS;
}

// ---------------- layer 1: gather + MLP (16 -> 64 -> 32) ----------------
__global__ __launch_bounds__(256) void mlp1_kernel(
    const float* __restrict__ x0, const int* __restrict__ offs, const int* __restrict__ csr,
    const float* __restrict__ W1, const float* __restrict__ b1,
    const float* __restrict__ W2, const float* __restrict__ b2,
    float* __restrict__ h1out) {
    __shared__ float W1t[C_IN * H1];    // W1t[j*16+c] = W1[c*64+j]
    __shared__ float W2s[H1 * C_OUT];
    __shared__ float b1s[H1];
    __shared__ float b2s[C_OUT];
    for (int i = threadIdx.x; i < C_IN * H1; i += 256) {
        int j = i >> 4, c = i & 15;
        W1t[i] = W1[c * H1 + j];
    }
    for (int i = threadIdx.x; i < H1 * C_OUT; i += 256) W2s[i] = W2[i];
    if (threadIdx.x < H1) b1s[threadIdx.x] = b1[threadIdx.x];
    if (threadIdx.x < C_OUT) b2s[threadIdx.x] = b2[threadIdx.x];
    __syncthreads();

    int slice, blk;
    map_block(blockIdx.x, slice, blk);
    int row0 = blk * 512 + threadIdx.x * 2;
    if (row0 >= N) return;
    const float* xs = x0 + (size_t)slice * N * C_IN;

    float ha[C_IN], hb[C_IN];
    {
        const float4* r = reinterpret_cast<const float4*>(xs + (size_t)row0 * C_IN);
        #pragma unroll
        for (int q = 0; q < 4; ++q) { float4 v = r[q];     ha[4*q]=v.x; ha[4*q+1]=v.y; ha[4*q+2]=v.z; ha[4*q+3]=v.w; }
        #pragma unroll
        for (int q = 0; q < 4; ++q) { float4 v = r[q + 4]; hb[4*q]=v.x; hb[4*q+1]=v.y; hb[4*q+2]=v.z; hb[4*q+3]=v.w; }
    }
    // merged gather over both rows: two independent load chains per iteration
    int bega = offs[row0],     dega = offs[row0 + 1] - bega;
    int begb = offs[row0 + 1], degb = offs[row0 + 2] - begb;
    int kmax = dega > degb ? dega : degb;
    for (int k = 0; k < kmax; ++k) {
        if (k < dega) {
            int sv = csr[bega + k];
            const float4* rr = reinterpret_cast<const float4*>(xs + (size_t)sv * C_IN);
            #pragma unroll
            for (int q = 0; q < 4; ++q) { float4 v = rr[q]; ha[4*q]+=v.x; ha[4*q+1]+=v.y; ha[4*q+2]+=v.z; ha[4*q+3]+=v.w; }
        }
        if (k < degb) {
            int sv = csr[begb + k];
            const float4* rr = reinterpret_cast<const float4*>(xs + (size_t)sv * C_IN);
            #pragma unroll
            for (int q = 0; q < 4; ++q) { float4 v = rr[q]; hb[4*q]+=v.x; hb[4*q+1]+=v.y; hb[4*q+2]+=v.z; hb[4*q+3]+=v.w; }
        }
    }

    float acca[C_OUT], accb[C_OUT];
    #pragma unroll
    for (int o = 0; o < C_OUT; ++o) { acca[o] = b2s[o]; accb[o] = b2s[o]; }
    for (int j = 0; j < H1; ++j) {
        float tj0 = b1s[j], tj1 = b1s[j];
        const float4* w1r = reinterpret_cast<const float4*>(&W1t[j * C_IN]);
        #pragma unroll
        for (int q = 0; q < 4; ++q) {
            float4 w = w1r[q];
            tj0 += ha[4*q]*w.x + ha[4*q+1]*w.y + ha[4*q+2]*w.z + ha[4*q+3]*w.w;
            tj1 += hb[4*q]*w.x + hb[4*q+1]*w.y + hb[4*q+2]*w.z + hb[4*q+3]*w.w;
        }
        tj0 = fmaxf(tj0, 0.f); tj1 = fmaxf(tj1, 0.f);
        const float4* w2r = reinterpret_cast<const float4*>(&W2s[j * C_OUT]);
        #pragma unroll
        for (int q = 0; q < 8; ++q) {
            float4 w = w2r[q];
            acca[4*q]+=tj0*w.x; acca[4*q+1]+=tj0*w.y; acca[4*q+2]+=tj0*w.z; acca[4*q+3]+=tj0*w.w;
            accb[4*q]+=tj1*w.x; accb[4*q+1]+=tj1*w.y; accb[4*q+2]+=tj1*w.z; accb[4*q+3]+=tj1*w.w;
        }
    }
    float4* d0 = reinterpret_cast<float4*>(h1out + ((size_t)slice * N + row0) * C_OUT);
    #pragma unroll
    for (int q = 0; q < 8; ++q) d0[q]     = make_float4(acca[4*q], acca[4*q+1], acca[4*q+2], acca[4*q+3]);
    #pragma unroll
    for (int q = 0; q < 8; ++q) d0[8 + q] = make_float4(accb[4*q], accb[4*q+1], accb[4*q+2], accb[4*q+3]);
}

// ---------------- layer 2: gather + MLP (32 -> 128 -> 32) + relu ----------------
// MODE 0: coalesced write of relu(out) to h2 (s,n,c). MODE 1: direct strided write to (B,N,C,T).
template <int MODE>
__global__ __launch_bounds__(256) void mlp2_kernel(
    const float* __restrict__ h1, const int* __restrict__ offs, const int* __restrict__ csr,
    const float* __restrict__ W3, const float* __restrict__ b3,
    const float* __restrict__ W4, const float* __restrict__ b4,
    float* __restrict__ outp) {
    __shared__ float W3t[C_OUT * H2];   // W3t[j*32+c] = W3[c*128+j]
    __shared__ float W4s[H2 * C_OUT];
    __shared__ float b3s[H2];
    __shared__ float b4s[C_OUT];
    for (int i = threadIdx.x; i < C_OUT * H2; i += 256) {
        int j = i >> 5, c = i & 31;
        W3t[i] = W3[c * H2 + j];
    }
    for (int i = threadIdx.x; i < H2 * C_OUT; i += 256) W4s[i] = W4[i];
    if (threadIdx.x < H2) b3s[threadIdx.x] = b3[threadIdx.x];
    if (threadIdx.x < C_OUT) b4s[threadIdx.x] = b4[threadIdx.x];
    __syncthreads();

    int slice, blk;
    map_block(blockIdx.x, slice, blk);
    int row0 = blk * 512 + threadIdx.x * 2;
    if (row0 >= N) return;
    const float* hs = h1 + (size_t)slice * N * C_OUT;

    float ha[C_OUT], hb[C_OUT];
    {
        const float4* r = reinterpret_cast<const float4*>(hs + (size_t)row0 * C_OUT);
        #pragma unroll
        for (int q = 0; q < 8; ++q) { float4 v = r[q];     ha[4*q]=v.x; ha[4*q+1]=v.y; ha[4*q+2]=v.z; ha[4*q+3]=v.w; }
        #pragma unroll
        for (int q = 0; q < 8; ++q) { float4 v = r[q + 8]; hb[4*q]=v.x; hb[4*q+1]=v.y; hb[4*q+2]=v.z; hb[4*q+3]=v.w; }
    }
    int bega = offs[row0],     dega = offs[row0 + 1] - bega;
    int begb = offs[row0 + 1], degb = offs[row0 + 2] - begb;
    int kmax = dega > degb ? dega : degb;
    for (int k = 0; k < kmax; ++k) {
        if (k < dega) {
            int sv = csr[bega + k];
            const float4* rr = reinterpret_cast<const float4*>(hs + (size_t)sv * C_OUT);
            #pragma unroll
            for (int q = 0; q < 8; ++q) { float4 v = rr[q]; ha[4*q]+=v.x; ha[4*q+1]+=v.y; ha[4*q+2]+=v.z; ha[4*q+3]+=v.w; }
        }
        if (k < degb) {
            int sv = csr[begb + k];
            const float4* rr = reinterpret_cast<const float4*>(hs + (size_t)sv * C_OUT);
            #pragma unroll
            for (int q = 0; q < 8; ++q) { float4 v = rr[q]; hb[4*q]+=v.x; hb[4*q+1]+=v.y; hb[4*q+2]+=v.z; hb[4*q+3]+=v.w; }
        }
    }

    float acca[C_OUT], accb[C_OUT];
    #pragma unroll
    for (int o = 0; o < C_OUT; ++o) { acca[o] = b4s[o]; accb[o] = b4s[o]; }
    for (int j = 0; j < H2; ++j) {
        float tj0 = b3s[j], tj1 = b3s[j];
        const float4* w3r = reinterpret_cast<const float4*>(&W3t[j * C_OUT]);
        #pragma unroll
        for (int q = 0; q < 8; ++q) {
            float4 w = w3r[q];
            tj0 += ha[4*q]*w.x + ha[4*q+1]*w.y + ha[4*q+2]*w.z + ha[4*q+3]*w.w;
            tj1 += hb[4*q]*w.x + hb[4*q+1]*w.y + hb[4*q+2]*w.z + hb[4*q+3]*w.w;
        }
        tj0 = fmaxf(tj0, 0.f); tj1 = fmaxf(tj1, 0.f);
        const float4* w4r = reinterpret_cast<const float4*>(&W4s[j * C_OUT]);
        #pragma unroll
        for (int q = 0; q < 8; ++q) {
            float4 w = w4r[q];
            acca[4*q]+=tj0*w.x; acca[4*q+1]+=tj0*w.y; acca[4*q+2]+=tj0*w.z; acca[4*q+3]+=tj0*w.w;
            accb[4*q]+=tj1*w.x; accb[4*q+1]+=tj1*w.y; accb[4*q+2]+=tj1*w.z; accb[4*q+3]+=tj1*w.w;
        }
    }
    if (MODE == 0) {
        float4* d0 = reinterpret_cast<float4*>(outp + ((size_t)slice * N + row0) * C_OUT);
        #pragma unroll
        for (int q = 0; q < 8; ++q)
            d0[q] = make_float4(fmaxf(acca[4*q],0.f), fmaxf(acca[4*q+1],0.f), fmaxf(acca[4*q+2],0.f), fmaxf(acca[4*q+3],0.f));
        #pragma unroll
        for (int q = 0; q < 8; ++q)
            d0[8+q] = make_float4(fmaxf(accb[4*q],0.f), fmaxf(accb[4*q+1],0.f), fmaxf(accb[4*q+2],0.f), fmaxf(accb[4*q+3],0.f));
    } else {
        int bb = slice / T, t = slice - bb * T;
        size_t obase = ((size_t)(bb * N + row0) * C_OUT) * T + t;
        #pragma unroll
        for (int c = 0; c < C_OUT; ++c) outp[obase + (size_t)c * T] = fmaxf(acca[c], 0.f);
        obase += (size_t)C_OUT * T;
        #pragma unroll
        for (int c = 0; c < C_OUT; ++c) outp[obase + (size_t)c * T] = fmaxf(accb[c], 0.f);
    }
}

// ---------------- output transpose: (S,N,32) -> (B,N,32,T) ----------------
// block: b = i&7 (matches producing XCD), tile of 8 n.
__global__ __launch_bounds__(256) void out_transpose_kernel(const float* __restrict__ h2,
                                                            float* __restrict__ out) {
    __shared__ float lds[8 * 800];       // [n_l][c*25 + t], padded
    int i = blockIdx.x;
    int b = i & 7;
    int tile = i >> 3;                   // 0..1249
    int n0 = tile * 8;
    int c = threadIdx.x & 31, n_l = threadIdx.x >> 5;
    #pragma unroll
    for (int t = 0; t < T; ++t) {
        float v = h2[((size_t)(b * T + t) * N + n0 + n_l) * C_OUT + c];
        lds[n_l * 800 + c * 25 + t] = v;
    }
    __syncthreads();
    size_t obase = (size_t)(b * N + n0) * (C_OUT * T);
    #pragma unroll
    for (int it = 0; it < 24; ++it) {
        int f = it * 256 + threadIdx.x;  // f = n*768 + c*24 + t
        int n = f / 768;
        int rem = f - n * 768;
        int c2 = rem / 24;
        int t2 = rem - c2 * 24;
        out[obase + f] = lds[n * 800 + c2 * 25 + t2];
    }
}

extern "C" void kernel_launch(void* const* d_in, const int* in_sizes, int n_in,
                              void* d_out, int out_size, void* d_ws, size_t ws_size,
                              hipStream_t stream) {
    const float* x   = (const float*)d_in[0];
    const int*   ei  = (const int*)d_in[1];
    const float* W1  = (const float*)d_in[2];
    const float* b1  = (const float*)d_in[3];
    const float* W2  = (const float*)d_in[4];
    const float* b2  = (const float*)d_in[5];
    const float* W3  = (const float*)d_in[6];
    const float* b3  = (const float*)d_in[7];
    const float* W4  = (const float*)d_in[8];
    const float* b4  = (const float*)d_in[9];
    float* out = (float*)d_out;

    const int* srcp = ei;
    const int* dstp = ei + E;

    size_t x0_b = (size_t)S * N * C_IN * 4;      // 122.88 MB
    size_t h1_b = (size_t)S * N * C_OUT * 4;     // 245.76 MB
    size_t h2_b = h1_b;
    size_t meta_b = (size_t)(N + (N + 1) + N + E) * sizeof(int);

    char* ws = (char*)d_ws;
    float* x0 = (float*)ws;
    float* h1 = (float*)(ws + x0_b);
    bool modeA = ws_size >= x0_b + h1_b + h2_b + meta_b;
    float* h2   = modeA ? (float*)(ws + x0_b + h1_b) : nullptr;
    char* meta  = ws + x0_b + h1_b + (modeA ? h2_b : 0);
    int* counts = (int*)meta;
    int* offs   = counts + N;
    int* cursor = offs + N + 1;
    int* csr    = cursor + N;

    hipMemsetAsync(counts, 0, (size_t)(N + (N + 1) + N) * sizeof(int), stream);

    hist_kernel<<<(E + 255) / 256, 256, 0, stream>>>(dstp, counts);
    scan_kernel<<<1, 1024, 0, stream>>>(counts, offs);
    fill_kernel<<<(E + 255) / 256, 256, 0, stream>>>(srcp, dstp, offs, cursor, csr);

    in_transpose_kernel<<<B * (N / 16), 256, 0, stream>>>(x, x0);

    mlp1_kernel<<<GRID_MLP, 256, 0, stream>>>(x0, offs, csr, W1, b1, W2, b2, h1);
    if (modeA) {
        mlp2_kernel<0><<<GRID_MLP, 256, 0, stream>>>(h1, offs, csr, W3, b3, W4, b4, h2);
        out_transpose_kernel<<<B * (N / 8), 256, 0, stream>>>(h2, out);
    } else {
        mlp2_kernel<1><<<GRID_MLP, 256, 0, stream>>>(h1, offs, csr, W3, b3, W4, b4, out);
    }
}

// Round 5
// 1073.422 us; speedup vs baseline: 2.3668x; 1.7619x over previous
//
#include <hip/hip_runtime.h>

// Problem constants
constexpr int B = 8, N = 10000, C_IN = 16, T = 24, C_OUT = 32, E = 160000;
constexpr int S = B * T;                 // 192 graph slices
constexpr int H1 = 64;                   // 4*C_IN
constexpr int H2 = 128;                  // 4*C_OUT
constexpr int NXCD = 8;
constexpr int SPX = S / NXCD;            // 24 slices per XCD
constexpr int BPS = 79;                  // blocks per slice (128 rows/block, 78*128+16=10000)
constexpr int GRID_GIN = NXCD * SPX * BPS;   // 15168

typedef __attribute__((ext_vector_type(8))) short short8;   // 8 bf16 (4 VGPRs)
typedef __attribute__((ext_vector_type(4))) float f32x4;    // MFMA accumulator

__device__ inline unsigned short f2bf(float f) {            // RNE fp32->bf16
    unsigned u = __float_as_uint(f);
    u += 0x7fffu + ((u >> 16) & 1);
    return (unsigned short)(u >> 16);
}
__device__ inline unsigned pk2(float lo, float hi) {        // pack 2 bf16 into dword
    unsigned ul = __float_as_uint(lo);
    ul = (ul + 0x7fffu + ((ul >> 16) & 1)) >> 16;
    unsigned uh = __float_as_uint(hi);
    uh = (uh + 0x7fffu + ((uh >> 16) & 1)) & 0xffff0000u;
    return ul | uh;
}
__device__ inline void addbf8(float acc[8], uint4 v) {      // 8 bf16 -> fp32 add
    acc[0] += __uint_as_float(v.x << 16);
    acc[1] += __uint_as_float(v.x & 0xffff0000u);
    acc[2] += __uint_as_float(v.y << 16);
    acc[3] += __uint_as_float(v.y & 0xffff0000u);
    acc[4] += __uint_as_float(v.z << 16);
    acc[5] += __uint_as_float(v.z & 0xffff0000u);
    acc[6] += __uint_as_float(v.w << 16);
    acc[7] += __uint_as_float(v.w & 0xffff0000u);
}

// ---------------- CSR build ----------------
__global__ void hist_kernel(const int* __restrict__ dst, int* __restrict__ counts) {
    int e = blockIdx.x * blockDim.x + threadIdx.x;
    if (e < E) atomicAdd(&counts[dst[e]], 1);
}

__global__ void scan_kernel(const int* __restrict__ counts, int* __restrict__ offs) {
    __shared__ int lds[1024];
    __shared__ int base_s;
    int tid = threadIdx.x;
    if (tid == 0) base_s = 0;
    __syncthreads();
    constexpr int CHUNKS = (N + 1023) / 1024;
    for (int chunk = 0; chunk < CHUNKS; ++chunk) {
        int i = chunk * 1024 + tid;
        int v = (i < N) ? counts[i] : 0;
        lds[tid] = v;
        __syncthreads();
        for (int off = 1; off < 1024; off <<= 1) {
            int add = (tid >= off) ? lds[tid - off] : 0;
            __syncthreads();
            lds[tid] += add;
            __syncthreads();
        }
        int incl = lds[tid];
        int excl = base_s + incl - v;
        if (i < N) offs[i] = excl;
        if (i == N - 1) offs[N] = excl + v;
        __syncthreads();
        if (tid == 1023) base_s += lds[1023];
        __syncthreads();
    }
}

__global__ void fill_kernel(const int* __restrict__ src, const int* __restrict__ dst,
                            const int* __restrict__ offs, int* __restrict__ cursor,
                            int* __restrict__ csr) {
    int e = blockIdx.x * blockDim.x + threadIdx.x;
    if (e >= E) return;
    int d = dst[e];
    int pos = atomicAdd(&cursor[d], 1);
    csr[offs[d] + pos] = src[e];
}

// ---------------- weight pack: fragment-order bf16 ----------------
// A-pack (for transposed GEMM1): pA[(mt*64+l)*8+i] = Wa[c*H + j], j=16mt+(l&15), c=8*(l>>4)+i (0 if c>=C)
// B-pack (GEMM2):               pB[((kt*2+nt)*64+l)*8+i] = Wb[k*32 + 16nt + (l&15)], k=32kt+8*(l>>4)+i
__global__ void pack_kernel(const float* __restrict__ W1, const float* __restrict__ W2,
                            const float* __restrict__ W3, const float* __restrict__ W4,
                            unsigned short* __restrict__ pA1, unsigned short* __restrict__ pB1,
                            unsigned short* __restrict__ pA2, unsigned short* __restrict__ pB2) {
    int tid = blockIdx.x * blockDim.x + threadIdx.x;
    int stride = gridDim.x * blockDim.x;
    for (int idx = tid; idx < (H1/16)*512; idx += stride) {           // pA1
        int mt = idx >> 9, r = idx & 511, l = r >> 3, i = r & 7;
        int jj = 16*mt + (l & 15), cc = 8*(l >> 4) + i;
        pA1[idx] = f2bf(cc < C_IN ? W1[cc * H1 + jj] : 0.f);
    }
    for (int idx = tid; idx < (H1/32)*2*512; idx += stride) {         // pB1
        int kt = idx >> 10, q = idx & 1023, nt = q >> 9, r = q & 511, l = r >> 3, i = r & 7;
        int k = 32*kt + 8*(l >> 4) + i;
        pB1[idx] = f2bf(W2[k * 32 + 16*nt + (l & 15)]);
    }
    for (int idx = tid; idx < (H2/16)*512; idx += stride) {           // pA2
        int mt = idx >> 9, r = idx & 511, l = r >> 3, i = r & 7;
        int jj = 16*mt + (l & 15), cc = 8*(l >> 4) + i;
        pA2[idx] = f2bf(W3[cc * H2 + jj]);
    }
    for (int idx = tid; idx < (H2/32)*2*512; idx += stride) {         // pB2
        int kt = idx >> 10, q = idx & 1023, nt = q >> 9, r = q & 511, l = r >> 3, i = r & 7;
        int k = 32*kt + 8*(l >> 4) + i;
        pB2[idx] = f2bf(W4[k * 32 + 16*nt + (l & 15)]);
    }
}

// ---------------- input transpose: (B,N,16,T) fp32 -> (S,N,16) bf16 ----------------
__global__ __launch_bounds__(256) void in_transpose_kernel(const float* __restrict__ x,
                                                           unsigned short* __restrict__ x0) {
    __shared__ float lds[16 * 400];
    int b = blockIdx.x / (N / 16);
    int tile = blockIdx.x - b * (N / 16);
    int n0 = tile * 16;
    size_t ibase = ((size_t)b * N + n0) * (C_IN * T);
    #pragma unroll
    for (int it = 0; it < 24; ++it) {
        int f = it * 256 + threadIdx.x;      // f = n_l*384 + c*24 + t
        int n_l = f / 384;
        int rem = f - n_l * 384;
        int c = rem / 24;
        int t = rem - c * 24;
        lds[n_l * 400 + c * 25 + t] = x[ibase + f];
    }
    __syncthreads();
    int n_l = threadIdx.x >> 4, c = threadIdx.x & 15;
    #pragma unroll
    for (int t = 0; t < T; ++t)
        x0[((size_t)(b * T + t) * N + n0) * C_IN + threadIdx.x] = f2bf(lds[n_l * 400 + c * 25 + t]);
}

// ---------------- fused GIN layer: gather-agg (fp32) + MFMA MLP (bf16) ----------------
// hin (S,N,C) bf16 -> hout (S,N,32) bf16.  relu between linears; FINAL adds output relu.
// Per block: 256 thr = 4 waves, 128 rows; each wave 2 tiles of 16 rows. No barriers.
template <int C, int H, bool FINAL>
__global__ __launch_bounds__(256) void gin_kernel(
    const unsigned short* __restrict__ hin,
    const int* __restrict__ offs, const int* __restrict__ csr,
    const unsigned short* __restrict__ pA, const unsigned short* __restrict__ pB,
    const float* __restrict__ ba, const float* __restrict__ bb,
    unsigned short* __restrict__ hout) {
    constexpr int MT = H / 16;
    constexpr int KT = H / 32;
    constexpr int RS1 = 80;              // A1 tile row stride (32 bf16 + pad), 16B-aligned
    constexpr int RS2 = 2 * H + 16;      // hidden tile row stride, 16B-aligned
    constexpr int WLDS = 16 * RS1 + 16 * RS2;
    __shared__ unsigned char smem[4 * WLDS];

    int wave = threadIdx.x >> 6;
    int lane = threadIdx.x & 63;
    int g = lane >> 4;                   // 0..3 (k-group)
    int c16 = lane & 15;
    unsigned char* A1 = smem + wave * WLDS;
    unsigned char* HB = A1 + 16 * RS1;

    int xcd = blockIdx.x & (NXCD - 1);
    int j = blockIdx.x >> 3;
    int slice = xcd * SPX + j / BPS;
    int blk = j % BPS;

    // fragment preload (one dwordx4 per frag per lane)
    const short8* pAv = (const short8*)pA;
    const short8* pBv = (const short8*)pB;
    short8 pa[MT];
    #pragma unroll
    for (int mt = 0; mt < MT; ++mt) pa[mt] = pAv[mt * 64 + lane];
    short8 pbf[KT][2];
    #pragma unroll
    for (int kt = 0; kt < KT; ++kt)
        #pragma unroll
        for (int nt = 0; nt < 2; ++nt) pbf[kt][nt] = pBv[(kt * 2 + nt) * 64 + lane];
    float bias1[MT * 4];
    #pragma unroll
    for (int mt = 0; mt < MT; ++mt)
        #pragma unroll
        for (int r = 0; r < 4; ++r) bias1[mt * 4 + r] = ba[16 * mt + 4 * g + r];
    float bias2[2];
    #pragma unroll
    for (int nt = 0; nt < 2; ++nt) bias2[nt] = bb[16 * nt + c16];

    const unsigned short* hs = hin + (size_t)slice * N * C;
    const f32x4 zero4 = {0.f, 0.f, 0.f, 0.f};

    for (int t = 0; t < 2; ++t) {
        int n0t = blk * 128 + wave * 32 + t * 16;
        if (n0t >= N) break;

        // ---- aggregation: 4 lanes per row, 8 channels per lane, fp32 ----
        int arow = lane >> 2, g4 = lane & 3;
        int row = n0t + arow;
        float acc[8];
        #pragma unroll
        for (int q = 0; q < 8; ++q) acc[q] = 0.f;
        if (C == 32 || g4 < 2) {
            uint4 own = *(const uint4*)(hs + (size_t)row * C + g4 * 8);
            addbf8(acc, own);
            int beg = offs[row];
            int deg = offs[row + 1] - beg;
            for (int e = 0; e < deg; ++e) {
                int sv = csr[beg + e];
                uint4 nb = *(const uint4*)(hs + (size_t)sv * C + g4 * 8);
                addbf8(acc, nb);
            }
        }
        uint4 w;
        w.x = pk2(acc[0], acc[1]); w.y = pk2(acc[2], acc[3]);
        w.z = pk2(acc[4], acc[5]); w.w = pk2(acc[6], acc[7]);
        *(uint4*)(A1 + arow * RS1 + g4 * 16) = w;   // zero-padded K for C=16

        // ---- GEMM1 (transposed): D1[mt] = Wa^T-tile x h^T -> lane holds h2pre[row=c16][j=16mt+4g+r]
        short8 a1 = *(const short8*)(A1 + c16 * RS1 + g * 16);
        f32x4 d1[MT];
        #pragma unroll
        for (int mt = 0; mt < MT; ++mt)
            d1[mt] = __builtin_amdgcn_mfma_f32_16x16x32_bf16(pa[mt], a1, zero4, 0, 0, 0);
        #pragma unroll
        for (int mt = 0; mt < MT; ++mt) {
            float v0 = fmaxf(d1[mt][0] + bias1[mt * 4 + 0], 0.f);
            float v1 = fmaxf(d1[mt][1] + bias1[mt * 4 + 1], 0.f);
            float v2 = fmaxf(d1[mt][2] + bias1[mt * 4 + 2], 0.f);
            float v3 = fmaxf(d1[mt][3] + bias1[mt * 4 + 3], 0.f);
            uint2 u; u.x = pk2(v0, v1); u.y = pk2(v2, v3);
            *(uint2*)(HB + c16 * RS2 + mt * 32 + g * 8) = u;   // h2[row=c16][j..j+3] bf16
        }

        // ---- GEMM2: O = h2 x Wb ----
        f32x4 d2a = zero4, d2b = zero4;
        #pragma unroll
        for (int kt = 0; kt < KT; ++kt) {
            short8 a2 = *(const short8*)(HB + c16 * RS2 + kt * 64 + g * 16);
            d2a = __builtin_amdgcn_mfma_f32_16x16x32_bf16(a2, pbf[kt][0], d2a, 0, 0, 0);
            d2b = __builtin_amdgcn_mfma_f32_16x16x32_bf16(a2, pbf[kt][1], d2b, 0, 0, 0);
        }

        // ---- store (S,N,32) bf16: lane holds rows 4g+r, cols {c16, 16+c16} ----
        #pragma unroll
        for (int r = 0; r < 4; ++r) {
            float va = d2a[r] + bias2[0];
            float vb = d2b[r] + bias2[1];
            if (FINAL) { va = fmaxf(va, 0.f); vb = fmaxf(vb, 0.f); }
            size_t rb = ((size_t)slice * N + n0t + 4 * g + r) * 32;
            hout[rb + c16] = f2bf(va);
            hout[rb + 16 + c16] = f2bf(vb);
        }
    }
}

// ---------------- output transpose: (S,N,32) bf16 -> (B,N,32,T) fp32 ----------------
__global__ __launch_bounds__(256) void out_transpose_kernel(const unsigned short* __restrict__ h2,
                                                            float* __restrict__ out) {
    __shared__ float lds[8 * 800];
    int i = blockIdx.x;
    int b = i & 7;
    int tile = i >> 3;
    int n0 = tile * 8;
    int c = threadIdx.x & 31, n_l = threadIdx.x >> 5;
    #pragma unroll
    for (int t = 0; t < T; ++t) {
        unsigned short v = h2[((size_t)(b * T + t) * N + n0 + n_l) * 32 + c];
        lds[n_l * 800 + c * 25 + t] = __uint_as_float((unsigned)v << 16);
    }
    __syncthreads();
    size_t obase = (size_t)(b * N + n0) * (C_OUT * T);
    #pragma unroll
    for (int it = 0; it < 24; ++it) {
        int f = it * 256 + threadIdx.x;  // f = n*768 + c*24 + t
        int n = f / 768;
        int rem = f - n * 768;
        int c2 = rem / 24;
        int t2 = rem - c2 * 24;
        out[obase + f] = lds[n * 800 + c2 * 25 + t2];
    }
}

extern "C" void kernel_launch(void* const* d_in, const int* in_sizes, int n_in,
                              void* d_out, int out_size, void* d_ws, size_t ws_size,
                              hipStream_t stream) {
    const float* x  = (const float*)d_in[0];
    const int*   ei = (const int*)d_in[1];
    const float* W1 = (const float*)d_in[2];
    const float* b1 = (const float*)d_in[3];
    const float* W2 = (const float*)d_in[4];
    const float* b2 = (const float*)d_in[5];
    const float* W3 = (const float*)d_in[6];
    const float* b3 = (const float*)d_in[7];
    const float* W4 = (const float*)d_in[8];
    const float* b4 = (const float*)d_in[9];
    float* out = (float*)d_out;

    const int* srcp = ei;
    const int* dstp = ei + E;

    size_t x0_b = (size_t)S * N * C_IN * 2;      // 61.44 MB bf16
    size_t h1_b = (size_t)S * N * C_OUT * 2;     // 122.88 MB bf16
    size_t h2_b = h1_b;
    size_t pA1_b = (size_t)(H1/16) * 512 * 2;    // 4 KB
    size_t pB1_b = (size_t)(H1/32) * 2 * 512 * 2;
    size_t pA2_b = (size_t)(H2/16) * 512 * 2;
    size_t pB2_b = (size_t)(H2/32) * 2 * 512 * 2;

    char* ws = (char*)d_ws;
    unsigned short* x0 = (unsigned short*)ws;
    unsigned short* h1 = (unsigned short*)(ws + x0_b);
    unsigned short* h2 = (unsigned short*)(ws + x0_b + h1_b);
    unsigned short* pA1 = (unsigned short*)(ws + x0_b + h1_b + h2_b);
    unsigned short* pB1 = (unsigned short*)((char*)pA1 + pA1_b);
    unsigned short* pA2 = (unsigned short*)((char*)pB1 + pB1_b);
    unsigned short* pB2 = (unsigned short*)((char*)pA2 + pA2_b);
    int* counts = (int*)((char*)pB2 + pB2_b);
    int* offs   = counts + N;
    int* cursor = offs + N + 1;
    int* csr    = cursor + N;

    hipMemsetAsync(counts, 0, (size_t)(N + (N + 1) + N) * sizeof(int), stream);

    hist_kernel<<<(E + 255) / 256, 256, 0, stream>>>(dstp, counts);
    scan_kernel<<<1, 1024, 0, stream>>>(counts, offs);
    fill_kernel<<<(E + 255) / 256, 256, 0, stream>>>(srcp, dstp, offs, cursor, csr);

    pack_kernel<<<8, 256, 0, stream>>>(W1, W2, W3, W4, pA1, pB1, pA2, pB2);
    in_transpose_kernel<<<B * (N / 16), 256, 0, stream>>>(x, x0);

    gin_kernel<16, 64, false><<<GRID_GIN, 256, 0, stream>>>(x0, offs, csr, pA1, pB1, b1, b2, h1);
    gin_kernel<32, 128, true><<<GRID_GIN, 256, 0, stream>>>(h1, offs, csr, pA2, pB2, b3, b4, h2);

    out_transpose_kernel<<<B * (N / 8), 256, 0, stream>>>(h2, out);
}

// Round 8
// 845.036 us; speedup vs baseline: 3.0065x; 1.2703x over previous
//
#include <hip/hip_runtime.h>

// Problem constants
constexpr int B = 8, N = 10000, C_IN = 16, T = 24, C_OUT = 32, E = 160000;
constexpr int S = B * T;                 // 192 graph slices
constexpr int H1 = 64;                   // 4*C_IN
constexpr int H2 = 128;                  // 4*C_OUT
constexpr int NXCD = 8;
constexpr int SPX = S / NXCD;            // 24 slices per XCD
constexpr int BPS = 79;                  // blocks per slice (128 rows/block)
constexpr int GRID_GIN = NXCD * SPX * BPS;   // 15168

typedef __attribute__((ext_vector_type(8))) short short8;   // 8 bf16 (4 VGPRs)
typedef __attribute__((ext_vector_type(4))) float f32x4;    // MFMA accumulator

__device__ inline unsigned short f2bf(float f) {            // RNE fp32->bf16
    unsigned u = __float_as_uint(f);
    u += 0x7fffu + ((u >> 16) & 1);
    return (unsigned short)(u >> 16);
}
__device__ inline unsigned pk2(float lo, float hi) {        // pack 2 bf16 into dword
    unsigned ul = __float_as_uint(lo);
    ul = (ul + 0x7fffu + ((ul >> 16) & 1)) >> 16;
    unsigned uh = __float_as_uint(hi);
    uh = (uh + 0x7fffu + ((uh >> 16) & 1)) & 0xffff0000u;
    return ul | uh;
}
__device__ inline void addbf8(float acc[8], uint4 v) {      // 8 bf16 -> fp32 add
    acc[0] += __uint_as_float(v.x << 16);
    acc[1] += __uint_as_float(v.x & 0xffff0000u);
    acc[2] += __uint_as_float(v.y << 16);
    acc[3] += __uint_as_float(v.y & 0xffff0000u);
    acc[4] += __uint_as_float(v.z << 16);
    acc[5] += __uint_as_float(v.z & 0xffff0000u);
    acc[6] += __uint_as_float(v.w << 16);
    acc[7] += __uint_as_float(v.w & 0xffff0000u);
}

// ---------------- CSR build ----------------
__global__ void hist_kernel(const int* __restrict__ dst, int* __restrict__ counts) {
    int e = blockIdx.x * blockDim.x + threadIdx.x;
    if (e < E) atomicAdd(&counts[dst[e]], 1);
}

__global__ void scan_kernel(const int* __restrict__ counts, int* __restrict__ offs) {
    __shared__ int lds[1024];
    __shared__ int base_s;
    int tid = threadIdx.x;
    if (tid == 0) base_s = 0;
    __syncthreads();
    constexpr int CHUNKS = (N + 1023) / 1024;
    for (int chunk = 0; chunk < CHUNKS; ++chunk) {
        int i = chunk * 1024 + tid;
        int v = (i < N) ? counts[i] : 0;
        lds[tid] = v;
        __syncthreads();
        for (int off = 1; off < 1024; off <<= 1) {
            int add = (tid >= off) ? lds[tid - off] : 0;
            __syncthreads();
            lds[tid] += add;
            __syncthreads();
        }
        int incl = lds[tid];
        int excl = base_s + incl - v;
        if (i < N) offs[i] = excl;
        if (i == N - 1) offs[N] = excl + v;
        __syncthreads();
        if (tid == 1023) base_s += lds[1023];
        __syncthreads();
    }
}

__global__ void fill_kernel(const int* __restrict__ src, const int* __restrict__ dst,
                            const int* __restrict__ offs, int* __restrict__ cursor,
                            int* __restrict__ csr) {
    int e = blockIdx.x * blockDim.x + threadIdx.x;
    if (e >= E) return;
    int d = dst[e];
    int pos = atomicAdd(&cursor[d], 1);
    csr[offs[d] + pos] = src[e];
}

// ---------------- weight pack: fragment-order bf16 ----------------
// A-pack (transposed GEMM1): pA[(mt*64+l)*8+i] = Wa[c*H + j], j=16mt+(l&15), c=8*(l>>4)+i (0 if c>=C)
// B-pack (GEMM2):            pB[((kt*2+nt)*64+l)*8+i] = Wb[k*32 + 16nt + (l&15)], k=32kt+8*(l>>4)+i
__global__ void pack_kernel(const float* __restrict__ W1, const float* __restrict__ W2,
                            const float* __restrict__ W3, const float* __restrict__ W4,
                            unsigned short* __restrict__ pA1, unsigned short* __restrict__ pB1,
                            unsigned short* __restrict__ pA2, unsigned short* __restrict__ pB2) {
    int tid = blockIdx.x * blockDim.x + threadIdx.x;
    int stride = gridDim.x * blockDim.x;
    for (int idx = tid; idx < (H1/16)*512; idx += stride) {           // pA1
        int mt = idx >> 9, r = idx & 511, l = r >> 3, i = r & 7;
        int jj = 16*mt + (l & 15), cc = 8*(l >> 4) + i;
        pA1[idx] = f2bf(cc < C_IN ? W1[cc * H1 + jj] : 0.f);
    }
    for (int idx = tid; idx < (H1/32)*2*512; idx += stride) {         // pB1
        int kt = idx >> 10, q = idx & 1023, nt = q >> 9, r = q & 511, l = r >> 3, i = r & 7;
        int k = 32*kt + 8*(l >> 4) + i;
        pB1[idx] = f2bf(W2[k * 32 + 16*nt + (l & 15)]);
    }
    for (int idx = tid; idx < (H2/16)*512; idx += stride) {           // pA2
        int mt = idx >> 9, r = idx & 511, l = r >> 3, i = r & 7;
        int jj = 16*mt + (l & 15), cc = 8*(l >> 4) + i;
        pA2[idx] = f2bf(W3[cc * H2 + jj]);
    }
    for (int idx = tid; idx < (H2/32)*2*512; idx += stride) {         // pB2
        int kt = idx >> 10, q = idx & 1023, nt = q >> 9, r = q & 511, l = r >> 3, i = r & 7;
        int k = 32*kt + 8*(l >> 4) + i;
        pB2[idx] = f2bf(W4[k * 32 + 16*nt + (l & 15)]);
    }
}

// ---------------- input transpose: (B,N,16,T) fp32 -> (S,N,16) bf16 ----------------
__global__ __launch_bounds__(256) void in_transpose_kernel(const float* __restrict__ x,
                                                           unsigned short* __restrict__ x0) {
    __shared__ float lds[16 * 400];
    int b = blockIdx.x / (N / 16);
    int tile = blockIdx.x - b * (N / 16);
    int n0 = tile * 16;
    size_t ibase = ((size_t)b * N + n0) * (C_IN * T);
    #pragma unroll
    for (int it = 0; it < 24; ++it) {
        int f = it * 256 + threadIdx.x;      // f = n_l*384 + c*24 + t
        int n_l = f / 384;
        int rem = f - n_l * 384;
        int c = rem / 24;
        int t = rem - c * 24;
        lds[n_l * 400 + c * 25 + t] = x[ibase + f];
    }
    __syncthreads();
    int n_l = threadIdx.x >> 4, c = threadIdx.x & 15;
    #pragma unroll
    for (int t = 0; t < T; ++t)
        x0[((size_t)(b * T + t) * N + n0) * C_IN + threadIdx.x] = f2bf(lds[n_l * 400 + c * 25 + t]);
}

// ---------------- fused GIN layer: gather-agg (fp32) + MFMA MLP (bf16) ----------------
// hin (S,N,C) bf16 -> hout (S,N,32) bf16.  relu between linears; FINAL adds output relu.
// Per block: 4 waves x 32 rows. Aggregation: C/8 lanes per row, unroll-4 edge loop.
template <int C, int H, bool FINAL>
__global__ __launch_bounds__(256, 6) void gin_kernel(
    const unsigned short* __restrict__ hin,
    const int* __restrict__ offs, const int* __restrict__ csr,
    const unsigned short* __restrict__ pA, const unsigned short* __restrict__ pB,
    const float* __restrict__ ba, const float* __restrict__ bb,
    unsigned short* __restrict__ hout) {
    constexpr int MT = H / 16;
    constexpr int KT = H / 32;
    constexpr int LPR = C / 8;           // lanes per row in aggregation (2 or 4)
    constexpr int RPP = 64 / LPR;        // rows per aggregation pass (32 or 16)
    constexpr int PASSES = 32 / RPP;     // 1 or 2
    constexpr int RS1 = 80;              // A tile row stride bytes (32 bf16 + pad)
    constexpr int RS2 = 2 * H + 16;      // hidden tile row stride bytes
    constexpr int WLDS = 32 * RS1 + 16 * RS2;
    __shared__ unsigned char smem[4 * WLDS];

    int wave = threadIdx.x >> 6;
    int lane = threadIdx.x & 63;
    int g = lane >> 4;                   // 0..3 (k-group)
    int c16 = lane & 15;
    unsigned char* A1 = smem + wave * WLDS;
    unsigned char* HB = A1 + 32 * RS1;

    int xcd = blockIdx.x & (NXCD - 1);
    int j = blockIdx.x >> 3;
    int slice = xcd * SPX + j / BPS;
    int blk = j % BPS;
    int wbase = blk * 128 + wave * 32;

    const unsigned short* hs = hin + (size_t)slice * N * C;
    const short8* pAv = (const short8*)pA;
    const short8* pBv = (const short8*)pB;
    const f32x4 zero4 = {0.f, 0.f, 0.f, 0.f};
    float bias2[2];
    bias2[0] = bb[c16];
    bias2[1] = bb[16 + c16];

    // ---- aggregation: fill A1 for 32 rows, fp32 accumulate, unroll-4 gathers ----
    int arow = lane / LPR;
    int g4 = lane % LPR;
    #pragma unroll
    for (int p = 0; p < PASSES; ++p) {
        int r32 = p * RPP + arow;        // 0..31
        int row = wbase + r32;
        float acc[8];
        #pragma unroll
        for (int q = 0; q < 8; ++q) acc[q] = 0.f;
        if (row < N) {
            uint4 own = *(const uint4*)(hs + (size_t)row * C + g4 * 8);
            int beg = offs[row];
            int deg = offs[row + 1] - beg;
            addbf8(acc, own);
            int e = 0;
            for (; e + 4 <= deg; e += 4) {
                int sv0 = csr[beg + e + 0];
                int sv1 = csr[beg + e + 1];
                int sv2 = csr[beg + e + 2];
                int sv3 = csr[beg + e + 3];
                uint4 n0 = *(const uint4*)(hs + (size_t)sv0 * C + g4 * 8);
                uint4 n1 = *(const uint4*)(hs + (size_t)sv1 * C + g4 * 8);
                uint4 n2 = *(const uint4*)(hs + (size_t)sv2 * C + g4 * 8);
                uint4 n3 = *(const uint4*)(hs + (size_t)sv3 * C + g4 * 8);
                addbf8(acc, n0); addbf8(acc, n1); addbf8(acc, n2); addbf8(acc, n3);
            }
            for (; e < deg; ++e) {
                int sv = csr[beg + e];
                uint4 nb = *(const uint4*)(hs + (size_t)sv * C + g4 * 8);
                addbf8(acc, nb);
            }
        }
        uint4 w;
        w.x = pk2(acc[0], acc[1]); w.y = pk2(acc[2], acc[3]);
        w.z = pk2(acc[4], acc[5]); w.w = pk2(acc[6], acc[7]);
        *(uint4*)(A1 + r32 * RS1 + g4 * 16) = w;
        if (C == 16) {                   // zero-fill K-pad (cols 16..31)
            uint4 z = {0u, 0u, 0u, 0u};
            *(uint4*)(A1 + r32 * RS1 + (2 + g4) * 16) = z;
        }
    }

    // ---- per 16-row tile: GEMM1 (transposed) -> relu -> GEMM2 -> store ----
    for (int t = 0; t < 2; ++t) {
        int n0t = wbase + t * 16;
        if (n0t >= N) break;

        short8 a1 = *(const short8*)(A1 + (t * 16 + c16) * RS1 + g * 16);
        #pragma unroll
        for (int mt = 0; mt < MT; ++mt) {
            short8 pa = pAv[mt * 64 + lane];
            f32x4 d1 = __builtin_amdgcn_mfma_f32_16x16x32_bf16(pa, a1, zero4, 0, 0, 0);
            float4 bs = *(const float4*)(ba + 16 * mt + 4 * g);
            float v0 = fmaxf(d1[0] + bs.x, 0.f);
            float v1 = fmaxf(d1[1] + bs.y, 0.f);
            float v2 = fmaxf(d1[2] + bs.z, 0.f);
            float v3 = fmaxf(d1[3] + bs.w, 0.f);
            uint2 u; u.x = pk2(v0, v1); u.y = pk2(v2, v3);
            *(uint2*)(HB + c16 * RS2 + mt * 32 + g * 8) = u;   // h2[row=c16][16mt+4g..+3]
        }

        f32x4 d2a = zero4, d2b = zero4;
        #pragma unroll
        for (int kt = 0; kt < KT; ++kt) {
            short8 a2 = *(const short8*)(HB + c16 * RS2 + kt * 64 + g * 16);
            short8 pb0 = pBv[(kt * 2 + 0) * 64 + lane];
            short8 pb1 = pBv[(kt * 2 + 1) * 64 + lane];
            d2a = __builtin_amdgcn_mfma_f32_16x16x32_bf16(a2, pb0, d2a, 0, 0, 0);
            d2b = __builtin_amdgcn_mfma_f32_16x16x32_bf16(a2, pb1, d2b, 0, 0, 0);
        }

        #pragma unroll
        for (int r = 0; r < 4; ++r) {
            float va = d2a[r] + bias2[0];
            float vb = d2b[r] + bias2[1];
            if (FINAL) { va = fmaxf(va, 0.f); vb = fmaxf(vb, 0.f); }
            size_t rb = ((size_t)slice * N + n0t + 4 * g + r) * 32;
            hout[rb + c16] = f2bf(va);
            hout[rb + 16 + c16] = f2bf(vb);
        }
    }
}

// ---------------- output transpose: (S,N,32) bf16 -> (B,N,32,T) fp32 ----------------
__global__ __launch_bounds__(256) void out_transpose_kernel(const unsigned short* __restrict__ h2,
                                                            float* __restrict__ out) {
    __shared__ float lds[8 * 800];
    int i = blockIdx.x;
    int b = i & 7;
    int tile = i >> 3;
    int n0 = tile * 8;
    int c = threadIdx.x & 31, n_l = threadIdx.x >> 5;
    #pragma unroll
    for (int t = 0; t < T; ++t) {
        unsigned short v = h2[((size_t)(b * T + t) * N + n0 + n_l) * 32 + c];
        lds[n_l * 800 + c * 25 + t] = __uint_as_float((unsigned)v << 16);
    }
    __syncthreads();
    size_t obase = (size_t)(b * N + n0) * (C_OUT * T);
    #pragma unroll
    for (int it = 0; it < 24; ++it) {
        int f = it * 256 + threadIdx.x;  // f = n*768 + c*24 + t
        int n = f / 768;
        int rem = f - n * 768;
        int c2 = rem / 24;
        int t2 = rem - c2 * 24;
        out[obase + f] = lds[n * 800 + c2 * 25 + t2];
    }
}

extern "C" void kernel_launch(void* const* d_in, const int* in_sizes, int n_in,
                              void* d_out, int out_size, void* d_ws, size_t ws_size,
                              hipStream_t stream) {
    const float* x  = (const float*)d_in[0];
    const int*   ei = (const int*)d_in[1];
    const float* W1 = (const float*)d_in[2];
    const float* b1 = (const float*)d_in[3];
    const float* W2 = (const float*)d_in[4];
    const float* b2 = (const float*)d_in[5];
    const float* W3 = (const float*)d_in[6];
    const float* b3 = (const float*)d_in[7];
    const float* W4 = (const float*)d_in[8];
    const float* b4 = (const float*)d_in[9];
    float* out = (float*)d_out;

    const int* srcp = ei;
    const int* dstp = ei + E;

    size_t x0_b = (size_t)S * N * C_IN * 2;      // 61.44 MB bf16
    size_t h1_b = (size_t)S * N * C_OUT * 2;     // 122.88 MB bf16
    size_t h2_b = h1_b;
    size_t pA1_b = (size_t)(H1/16) * 512 * 2;
    size_t pB1_b = (size_t)(H1/32) * 2 * 512 * 2;
    size_t pA2_b = (size_t)(H2/16) * 512 * 2;
    size_t pB2_b = (size_t)(H2/32) * 2 * 512 * 2;

    char* ws = (char*)d_ws;
    unsigned short* x0 = (unsigned short*)ws;
    unsigned short* h1 = (unsigned short*)(ws + x0_b);
    unsigned short* h2 = (unsigned short*)(ws + x0_b + h1_b);
    unsigned short* pA1 = (unsigned short*)(ws + x0_b + h1_b + h2_b);
    unsigned short* pB1 = (unsigned short*)((char*)pA1 + pA1_b);
    unsigned short* pA2 = (unsigned short*)((char*)pB1 + pB1_b);
    unsigned short* pB2 = (unsigned short*)((char*)pA2 + pA2_b);
    int* counts = (int*)((char*)pB2 + pB2_b);
    int* offs   = counts + N;
    int* cursor = offs + N + 1;
    int* csr    = cursor + N;

    hipMemsetAsync(counts, 0, (size_t)(N + (N + 1) + N) * sizeof(int), stream);

    hist_kernel<<<(E + 255) / 256, 256, 0, stream>>>(dstp, counts);
    scan_kernel<<<1, 1024, 0, stream>>>(counts, offs);
    fill_kernel<<<(E + 255) / 256, 256, 0, stream>>>(srcp, dstp, offs, cursor, csr);

    pack_kernel<<<8, 256, 0, stream>>>(W1, W2, W3, W4, pA1, pB1, pA2, pB2);
    in_transpose_kernel<<<B * (N / 16), 256, 0, stream>>>(x, x0);

    gin_kernel<16, 64, false><<<GRID_GIN, 256, 0, stream>>>(x0, offs, csr, pA1, pB1, b1, b2, h1);
    gin_kernel<32, 128, true><<<GRID_GIN, 256, 0, stream>>>(h1, offs, csr, pA2, pB2, b3, b4, h2);

    out_transpose_kernel<<<B * (N / 8), 256, 0, stream>>>(h2, out);
}